// Round 4
// baseline (100.250 us; speedup 1.0000x reference)
//
#include <hip/hip_runtime.h>

#define B_   512
#define T_   365
#define C_   10
#define P_   64
#define K_   3650   // T*C
#define K2_  1825   // K_ in float2
#define KP_  3712   // padded row (floats), zero tail; 16B-aligned rows
#define KP2_ 1856   // KP_ in float2
#define KP4_ 928    // KP_ in float4

// d_out flat offsets (floats), in reference return order
#define OFF_OUT0 0u          // output_seq [B,T,C]
#define OFF_IN   1868800u    // input_seq  [B,T,C]
#define OFF_DIST 3737600u    // distances  [B,P]
#define OFF_IDX  3770368u    // indices    [B]
#define OFF_LAB  3770880u    // label      [B]
#define OFF_MASK 3771392u    // mask       [B,T]

// ws layout (floats): [0, P_*KP_) padded protos ; then P_*T_ sp values
#define WS_SP_OFF (P_ * KP_)   // 237568

// blocks [0,928): repack protos into 16B-aligned zero-padded rows in ws.
// blocks [928,1020): sp[p*T_+t] = sum_c proto[p,t,c]^2
__global__ __launch_bounds__(256) void prep_kernel(
    const float* __restrict__ protos, float* __restrict__ ws)
{
    const int bid = blockIdx.x;
    if (bid < 928) {
        int j = bid * 256 + threadIdx.x;      // < P_*KP_ = 237568
        int p = j / KP_;
        int r = j - p * KP_;
        ws[j] = (r < K_) ? protos[(size_t)p * K_ + r] : 0.f;
    } else {
        int i = (bid - 928) * 256 + threadIdx.x;
        if (i < P_ * T_) {
            const float* pp = protos + (size_t)i * C_;
            float s = 0.f;
#pragma unroll
            for (int c = 0; c < C_; ++c) s = fmaf(pp[c], pp[c], s);
            ws[WS_SP_OFF + i] = s;
        }
    }
}

// One block per 2 batch rows; 1024 threads = 16 waves; wave w owns protos
// [4w,4w+4). d[b][p] = x2m[b] - 2*dot(xm[b],proto[p]) + sum_t m[b,t]*sp[p,t]
// (exactly the reference expansion). xm zero-padded in LDS; protos
// zero-padded in ws -> clean float4 K-loop, no tail fixup.
__global__ __launch_bounds__(1024) void dist_kernel(
    const float* __restrict__ x, const float* __restrict__ mask,
    const int* __restrict__ label, const float* __restrict__ protos,
    const float* __restrict__ ws, float* __restrict__ out)
{
    __shared__ float xm[2][KP_];    // masked x rows, zero-padded
    __shared__ float mrow[2][368];  // raw mask rows
    __shared__ float dist[2][64];
    __shared__ float wsum[16][2];
    __shared__ float x2s[2];
    __shared__ int   sel[2];

    const int tid  = threadIdx.x;
    const int lane = tid & 63;
    const int wv   = tid >> 6;      // 0..15
    const int b0   = blockIdx.x * 2;

    // ---- stage mask rows + fused mask echo ----
    if (tid < T_) {
        float m = mask[(size_t)b0 * T_ + tid];
        mrow[0][tid] = m;
        out[OFF_MASK + (size_t)b0 * T_ + tid] = m;
    }
    {
        int t2 = tid - 512;
        if (t2 >= 0 && t2 < T_) {
            float m = mask[(size_t)(b0 + 1) * T_ + t2];
            mrow[1][t2] = m;
            out[OFF_MASK + (size_t)(b0 + 1) * T_ + t2] = m;
        }
    }
    __syncthreads();

    // ---- stage masked x (float2: rows are 8B-aligned), fused input echo,
    //      accumulate x2m partials ----
    float s2[2] = {0.f, 0.f};
#pragma unroll
    for (int bb = 0; bb < 2; ++bb) {
        const float2* xr = (const float2*)(x + (size_t)(b0 + bb) * K_);
        float2*       er = (float2*)(out + OFF_IN + (size_t)(b0 + bb) * K_);
        float2*       sm = (float2*)&xm[bb][0];
        for (int i2 = tid; i2 < KP2_; i2 += 1024) {
            float2 v = {0.f, 0.f};
            if (i2 < K2_) {
                v = xr[i2];
                er[i2] = v;
                int e = i2 * 2;
                v.x *= mrow[bb][e / C_];
                v.y *= mrow[bb][(e + 1) / C_];
            }
            sm[i2] = v;
            s2[bb] = fmaf(v.x, v.x, fmaf(v.y, v.y, s2[bb]));
        }
    }
#pragma unroll
    for (int bb = 0; bb < 2; ++bb) {
        float v = s2[bb];
        for (int off = 32; off; off >>= 1) v += __shfl_down(v, off);
        if (lane == 0) wsum[wv][bb] = v;
    }
    __syncthreads();
    if (tid < 2) {
        float s = 0.f;
#pragma unroll
        for (int w = 0; w < 16; ++w) s += wsum[w][tid];
        x2s[tid] = s;
    }
    __syncthreads();

    // ---- main K-loop: xp dots, 4 protos x 2 rows per wave, float4 ----
    const int p0 = wv * 4;
    const float4* pw  = (const float4*)ws;            // padded protos
    const float4* xr0 = (const float4*)&xm[0][0];
    const float4* xr1 = (const float4*)&xm[1][0];

    float acc0[4] = {0.f, 0.f, 0.f, 0.f};
    float acc1[4] = {0.f, 0.f, 0.f, 0.f};

#pragma unroll 5
    for (int it = 0; it < 15; ++it) {
        const int i4  = it * 64 + lane;
        const bool ok = (i4 < KP4_);
        const int i4c = ok ? i4 : 0;
        float4 pv[4];
#pragma unroll
        for (int q = 0; q < 4; ++q)
            pv[q] = pw[(size_t)(p0 + q) * KP4_ + i4c];   // 4 indep L2 loads
        float4 u0 = xr0[i4c];
        float4 u1 = xr1[i4c];
        if (!ok) { u0.x=u0.y=u0.z=u0.w=0.f; u1.x=u1.y=u1.z=u1.w=0.f; }
#pragma unroll
        for (int q = 0; q < 4; ++q) {
            acc0[q] = fmaf(u0.x, pv[q].x, acc0[q]);
            acc0[q] = fmaf(u0.y, pv[q].y, acc0[q]);
            acc0[q] = fmaf(u0.z, pv[q].z, acc0[q]);
            acc0[q] = fmaf(u0.w, pv[q].w, acc0[q]);
            acc1[q] = fmaf(u1.x, pv[q].x, acc1[q]);
            acc1[q] = fmaf(u1.y, pv[q].y, acc1[q]);
            acc1[q] = fmaf(u1.z, pv[q].z, acc1[q]);
            acc1[q] = fmaf(u1.w, pv[q].w, acc1[q]);
        }
    }

    // ---- c-term (sp . mask) + combine + reduce ----
    const float* sp = ws + WS_SP_OFF;
#pragma unroll
    for (int q = 0; q < 4; ++q) {
        const float* spq = sp + (size_t)(p0 + q) * T_;
        float c0 = 0.f, c1 = 0.f;
        for (int t = lane; t < T_; t += 64) {
            float s = spq[t];
            c0 = fmaf(s, mrow[0][t], c0);
            c1 = fmaf(s, mrow[1][t], c1);
        }
        float v0 = fmaf(-2.f, acc0[q], c0);
        float v1 = fmaf(-2.f, acc1[q], c1);
        for (int off = 32; off; off >>= 1) {
            v0 += __shfl_down(v0, off);
            v1 += __shfl_down(v1, off);
        }
        if (lane == 0) {
            dist[0][p0 + q] = x2s[0] + v0;
            dist[1][p0 + q] = x2s[1] + v1;
        }
    }
    __syncthreads();

    // ---- write distances; per-wave argmin (first-occurrence tie-break) ----
    if (tid < 128) {
        int bb = tid >> 6;
        out[OFF_DIST + (size_t)(b0 + bb) * P_ + lane] = dist[bb][lane];
    }
    if (wv < 2) {
        const int bb = wv;
        float v = dist[bb][lane];
        int idx = lane;
        for (int off = 32; off; off >>= 1) {
            float ov = __shfl_down(v, off);
            int   oi = __shfl_down(idx, off);
            if (ov < v || (ov == v && oi < idx)) { v = ov; idx = oi; }
        }
        if (lane == 0) {
            sel[bb] = idx;
            const int b = b0 + bb;
            out[OFF_IDX + b] = (float)idx;
            out[OFF_LAB + b] = (float)label[b];
        }
    }
    __syncthreads();

    // ---- gather selected prototype rows into output_seq ----
#pragma unroll
    for (int bb = 0; bb < 2; ++bb) {
        const float2* src = (const float2*)(protos + (size_t)sel[bb] * K_);
        float2* dst = (float2*)(out + OFF_OUT0 + (size_t)(b0 + bb) * K_);
        for (int i2 = tid; i2 < K2_; i2 += 1024) dst[i2] = src[i2];
    }
}

extern "C" void kernel_launch(void* const* d_in, const int* in_sizes, int n_in,
                              void* d_out, int out_size, void* d_ws, size_t ws_size,
                              hipStream_t stream) {
    const float* x      = (const float*)d_in[0];
    const float* mask   = (const float*)d_in[1];
    const int*   label  = (const int*)d_in[2];
    const float* protos = (const float*)d_in[3];
    float* out = (float*)d_out;
    float* ws  = (float*)d_ws;   // ~1.04 MB used (ws is 256 MiB)

    prep_kernel<<<1020, 256, 0, stream>>>(protos, ws);
    dist_kernel<<<B_ / 2, 1024, 0, stream>>>(x, mask, label, protos, ws, out);
}

// Round 5
// 90.366 us; speedup vs baseline: 1.1094x; 1.1094x over previous
//
#include <hip/hip_runtime.h>

#define B_   512
#define T_   365
#define C_   10
#define P_   64
#define K_   3650   // T*C
#define K2_  1825   // K_ in float2
#define KP_  3712   // padded floats per LDS row (1856 float2 = 29*64)
#define KP2_ 1856

// d_out flat offsets (floats), in reference return order
#define OFF_OUT0 0u          // output_seq [B,T,C]
#define OFF_IN   1868800u    // input_seq  [B,T,C]
#define OFF_DIST 3737600u    // distances  [B,P]
#define OFF_IDX  3770368u    // indices    [B]
#define OFF_LAB  3770880u    // label      [B]
#define OFF_MASK 3771392u    // mask       [B,T]

// Grid: 512 blocks = (256 batch-pairs) x (2 proto-halves). 512 threads =
// 8 waves; wave w owns 4 protos of this block's 32. Difference form:
//   d[b][p] = sum_k (xm[k] - m[k]*proto[p][k])^2,  xm = m*x
// == reference expansion exactly (m binary). LDS zero-padded so padded
// lanes contribute 0; only proto loads need clamping. 2 blocks/CU
// co-resident (launch_bounds(512,4)) to overlap staging/compute phases
// across blocks and allow 128 VGPRs for deep load pipelining.
__global__ __launch_bounds__(512, 4) void dist_kernel(
    const float* __restrict__ x, const float* __restrict__ mask,
    const float* __restrict__ protos, float* __restrict__ out)
{
    __shared__ float xm[2][KP_];    // masked x rows, zero-padded
    __shared__ float mexp[2][KP_];  // per-element mask, zero-padded
    __shared__ float mrow[2][368];  // raw mask rows

    const int tid  = threadIdx.x;
    const int lane = tid & 63;
    const int wv   = tid >> 6;              // 0..7
    const int bp   = blockIdx.x >> 1;
    const int ph   = blockIdx.x & 1;        // proto half
    const int b0   = bp * 2;

    // ---- stage mask rows (+ echo from half 0 only) ----
    for (int t = tid; t < 2 * T_; t += 512) {
        int bb = t >= T_;
        int tt = t - bb * T_;
        float m = mask[(size_t)(b0 + bb) * T_ + tt];
        mrow[bb][tt] = m;
        if (ph == 0) out[OFF_MASK + (size_t)(b0 + bb) * T_ + tt] = m;
    }
    __syncthreads();

    // ---- build xm/mexp (float2; rows 8B-aligned) + fused input echo ----
#pragma unroll
    for (int bb = 0; bb < 2; ++bb) {
        const float2* xr = (const float2*)(x + (size_t)(b0 + bb) * K_);
        float2*       er = (float2*)(out + OFF_IN + (size_t)(b0 + bb) * K_);
        float2*       sx = (float2*)&xm[bb][0];
        float2*       sm = (float2*)&mexp[bb][0];
        for (int i2 = tid; i2 < KP2_; i2 += 512) {
            float2 v = {0.f, 0.f}, mm = {0.f, 0.f};
            if (i2 < K2_) {
                v = xr[i2];
                if (ph == 0) er[i2] = v;
                int e = i2 * 2;
                mm.x = mrow[bb][e / C_];
                mm.y = mrow[bb][(e + 1) / C_];
                v.x *= mm.x;
                v.y *= mm.y;
            }
            sx[i2] = v;
            sm[i2] = mm;
        }
    }
    __syncthreads();

    // ---- main loop: 4 protos x 2 rows per wave, 29 K-steps, unroll 4 ----
    const int p0 = ph * 32 + wv * 4;
    const float2* pr[4];
#pragma unroll
    for (int q = 0; q < 4; ++q)
        pr[q] = (const float2*)(protos + (size_t)(p0 + q) * K_);
    const float2* xr0 = (const float2*)&xm[0][0];
    const float2* xr1 = (const float2*)&xm[1][0];
    const float2* mr0 = (const float2*)&mexp[0][0];
    const float2* mr1 = (const float2*)&mexp[1][0];

    float acc0[4] = {0.f, 0.f, 0.f, 0.f};
    float acc1[4] = {0.f, 0.f, 0.f, 0.f};

#pragma unroll 4
    for (int it = 0; it < 29; ++it) {
        const int i2  = it * 64 + lane;            // < 1856 (LDS padded)
        const int i2c = i2 < K2_ ? i2 : (K2_ - 1); // clamp proto load only
        float2 pv[4];
#pragma unroll
        for (int q = 0; q < 4; ++q) pv[q] = pr[q][i2c];  // 4 indep loads
        const float2 u0 = xr0[i2], m0 = mr0[i2];
        const float2 u1 = xr1[i2], m1 = mr1[i2];
#pragma unroll
        for (int q = 0; q < 4; ++q) {
            float tx, ty;
            tx = fmaf(-pv[q].x, m0.x, u0.x); acc0[q] = fmaf(tx, tx, acc0[q]);
            ty = fmaf(-pv[q].y, m0.y, u0.y); acc0[q] = fmaf(ty, ty, acc0[q]);
            tx = fmaf(-pv[q].x, m1.x, u1.x); acc1[q] = fmaf(tx, tx, acc1[q]);
            ty = fmaf(-pv[q].y, m1.y, u1.y); acc1[q] = fmaf(ty, ty, acc1[q]);
        }
    }

    // ---- reduce and write final distances straight to d_out ----
#pragma unroll
    for (int q = 0; q < 4; ++q) {
        float v0 = acc0[q], v1 = acc1[q];
        for (int off = 32; off; off >>= 1) {
            v0 += __shfl_down(v0, off);
            v1 += __shfl_down(v1, off);
        }
        if (lane == 0) {
            out[OFF_DIST + (size_t)b0 * P_ + p0 + q]       = v0;
            out[OFF_DIST + (size_t)(b0 + 1) * P_ + p0 + q] = v1;
        }
    }
}

// One block per sample: argmin over 64 distances (first-occurrence
// tie-break), idx/label echo, gather selected proto row.
__global__ __launch_bounds__(256) void argmin_kernel(
    const int* __restrict__ label, const float* __restrict__ protos,
    float* __restrict__ out)
{
    __shared__ int sel;
    const int b    = blockIdx.x;
    const int tid  = threadIdx.x;
    const int lane = tid & 63;

    if (tid < 64) {
        float v = out[OFF_DIST + (size_t)b * P_ + lane];
        int idx = lane;
        for (int off = 32; off; off >>= 1) {
            float ov = __shfl_down(v, off);
            int   oi = __shfl_down(idx, off);
            if (ov < v || (ov == v && oi < idx)) { v = ov; idx = oi; }
        }
        if (lane == 0) {
            sel = idx;
            out[OFF_IDX + b] = (float)idx;
            out[OFF_LAB + b] = (float)label[b];
        }
    }
    __syncthreads();

    const float2* src = (const float2*)(protos + (size_t)sel * K_);
    float2* dst = (float2*)(out + OFF_OUT0 + (size_t)b * K_);
    for (int i2 = tid; i2 < K2_; i2 += 256) dst[i2] = src[i2];
}

extern "C" void kernel_launch(void* const* d_in, const int* in_sizes, int n_in,
                              void* d_out, int out_size, void* d_ws, size_t ws_size,
                              hipStream_t stream) {
    const float* x      = (const float*)d_in[0];
    const float* mask   = (const float*)d_in[1];
    const int*   label  = (const int*)d_in[2];
    const float* protos = (const float*)d_in[3];
    float* out = (float*)d_out;

    dist_kernel<<<512, 512, 0, stream>>>(x, mask, protos, out);
    argmin_kernel<<<B_, 256, 0, stream>>>(label, protos, out);
}